// Round 15
// baseline (360.882 us; speedup 1.0000x reference)
//
#include <hip/hip_runtime.h>
#include <cstdint>

#define NTOK 8192
#define DMODEL 1024
#define HDDIM 4096
#define NVEC 32

typedef float f32x4_v __attribute__((ext_vector_type(4)));
typedef __bf16 bf16x8 __attribute__((ext_vector_type(8)));
typedef unsigned short u16x4 __attribute__((ext_vector_type(4)));
typedef unsigned short u16x8 __attribute__((ext_vector_type(8)));

__device__ __forceinline__ unsigned short f2bf(float f) {
  union { float f; uint32_t u; } x; x.f = f;
  uint32_t r = (x.u + 0x7FFFu + ((x.u >> 16) & 1u)) >> 16;
  return (unsigned short)r;
}

__device__ __forceinline__ float gelu_fast(float x) {
  float t = x * x;
  float z = x * (2.3022082f + 0.1029440f * t);
  float e = exp2f(-z);
  return x / (1.0f + e);
}

#define VMCNT(n) asm volatile("s_waitcnt vmcnt(" #n ")" ::: "memory")

__device__ __forceinline__ void gload16(const unsigned short* g, unsigned short* lds)
{
  __builtin_amdgcn_global_load_lds((__attribute__((address_space(1))) void*)g,
                                   (__attribute__((address_space(3))) void*)lds,
                                   16, 0, 0);
}

// ---------------------------------------------------------------------------
// Reconstruct + transpose body: tile 16x256, staggered v (R12 config).
// outT[y][x] (bf16, ld=X) = sum_v c[v]*basis[v][x][y]
// ---------------------------------------------------------------------------
__device__ __forceinline__
void reconstruct_body(const float* __restrict__ basis,
                      const float* __restrict__ coeffs,
                      int e, unsigned short* __restrict__ outT,
                      int X, int Y, int tile, int stag, char* smem, int t)
{
  float (*lds)[260] = (float (*)[260])smem;
  const int xtiles = X >> 4;
  const int bx = tile % xtiles;
  const int by = tile / xtiles;
  const int x0 = bx << 4, y0 = by << 8;
  const int w  = t >> 6, l = t & 63;

  f32x4_v acc[4];
  #pragma unroll
  for (int i = 0; i < 4; ++i) acc[i] = (f32x4_v){0.f, 0.f, 0.f, 0.f};

  const size_t mat = (size_t)X * (size_t)Y;
  uint32_t roff[4];
  #pragma unroll
  for (int i = 0; i < 4; ++i)
    roff[i] = (uint32_t)(x0 + w * 4 + i) * (uint32_t)Y + (uint32_t)(y0 + l * 4);

  #pragma unroll 4
  for (int vv = 0; vv < NVEC; ++vv) {
    const int v = (vv + stag) & (NVEC - 1);
    const float cv = coeffs[e * NVEC + v];
    const float* pv = basis + (size_t)v * mat;
    #pragma unroll
    for (int i = 0; i < 4; ++i) {
      f32x4_v d = __builtin_nontemporal_load((const f32x4_v*)(pv + roff[i]));
      acc[i] += cv * d;
    }
  }

  #pragma unroll
  for (int i = 0; i < 4; ++i)
    *(f32x4_v*)&lds[w * 4 + i][l * 4] = acc[i];
  __syncthreads();

  const int y = y0 + t;
  u16x8 o0, o1;
  #pragma unroll
  for (int x = 0; x < 8; ++x)  o0[x] = f2bf(lds[x][t]);
  #pragma unroll
  for (int x = 0; x < 8; ++x)  o1[x] = f2bf(lds[8 + x][t]);
  unsigned short* dst = outT + (size_t)y * X + x0;
  *(u16x8*)dst = o0;
  *(u16x8*)(dst + 8) = o1;
}

// ---------------------------------------------------------------------------
// Phase 1: rec_up (0..1023) | cvt (1024..1535).  256 threads.
// ---------------------------------------------------------------------------
__global__ __launch_bounds__(256)
void p1_kernel(const float* __restrict__ inputs,
               const float* __restrict__ basis_up,
               const float* __restrict__ cup,
               const int* __restrict__ eidx_p,
               unsigned short* __restrict__ A_bf,
               unsigned short* __restrict__ WupT)
{
  __shared__ __align__(16) char smem[16 * 260 * 4];
  const int bid = blockIdx.x;
  if (bid < 1024) {
    reconstruct_body(basis_up, cup, *eidx_p, WupT, DMODEL, HDDIM, bid, bid,
                     smem, threadIdx.x);
  } else {
    const int n4 = NTOK * DMODEL / 4;
    const int stride = 512 * 256;
    for (int i = (bid - 1024) * 256 + threadIdx.x; i < n4; i += stride) {
      f32x4_v v = ((const f32x4_v*)inputs)[i];
      u16x4 u;
      #pragma unroll
      for (int j = 0; j < 4; ++j) u[j] = f2bf(v[j]);
      ((u16x4*)A_bf)[i] = u;
    }
  }
}

// ---------------------------------------------------------------------------
// Phase 2: g1 (even bids) OVERLAPPED with rec_dn (odd bids). Round-robin
// dispatch puts g1 on XCDs {0,2,4,6}, rec on {1,3,5,7}. 128 KB LDS.
// ---------------------------------------------------------------------------
__global__ __launch_bounds__(512)
void p2_kernel(const unsigned short* __restrict__ A,
               const unsigned short* __restrict__ Bt,
               unsigned short* __restrict__ Cbf,
               const float* __restrict__ basis_down,
               const float* __restrict__ cdn,
               const int* __restrict__ eidx_p,
               unsigned short* __restrict__ WdnT)
{
  constexpr int BM = 256, BN = 256, BK = 32, CHM = 8, CHN = 8;
  constexpr int FM = BM / 32, FN = BN / 64;
  constexpr int P = (FM * FN) / 16;
  constexpr int SLOT = (BM + BN) * BK * 2;     // 32 KB
  constexpr int L = SLOT / 16 / 512;           // 4
  constexpr int LPP = L / P;
  constexpr int ACH = BM * 4;
  constexpr int JA = ACH / 512;                // 2

  __shared__ __align__(16) char smem[4 * SLOT];  // 128 KB

  const int bid = blockIdx.x;

  if (bid & 1) {
    const int half = threadIdx.x >> 8;
    const int tile = (bid >> 1) * 2 + half;
    reconstruct_body(basis_down, cdn, *eidx_p, WdnT, HDDIM, DMODEL,
                     tile, bid + half, smem + half * 16640, threadIdx.x & 255);
    return;
  }

  const int gtile = bid >> 1;
  const int K = DMODEL, N = HDDIM;
  const int ncn = (N / BN) / CHN;
  const int xcd = gtile & 7;
  const int idx = gtile >> 3;
  const int bm  = (xcd / ncn) * CHM + idx / CHN;
  const int bn  = (xcd % ncn) * CHN + idx % CHN;
  const int m0 = bm * BM, n0 = bn * BN;

  const int tid = threadIdx.x;
  const int w = tid >> 6, l = tid & 63;
  const int wm = w >> 2, wn = w & 3;
  const int lrow = l & 15, lkc = l >> 4;

  uint32_t soff[L];
  #pragma unroll
  for (int j = 0; j < L; ++j) {
    const int q = tid + j * 512;
    if (j < JA) {
      const int r = q >> 2, cs = (q & 3) ^ ((r >> 1) & 3);
      soff[j] = (uint32_t)(m0 + r) * (uint32_t)K + cs * 8;
    } else {
      const int q2 = q - ACH;
      const int r = q2 >> 2, cs = (q2 & 3) ^ ((r >> 1) & 3);
      soff[j] = (uint32_t)(n0 + r) * (uint32_t)K + cs * 8;
    }
  }

  int aoff[FM], boff[FN];
  #pragma unroll
  for (int f = 0; f < FM; ++f) {
    const int r = wm * (BM / 2) + f * 16 + lrow;
    aoff[f] = r * 64 + ((lkc ^ ((r >> 1) & 3)) << 4);
  }
  #pragma unroll
  for (int n_ = 0; n_ < FN; ++n_) {
    const int r = wn * (BN / 4) + n_ * 16 + lrow;
    boff[n_] = BM * 64 + r * 64 + ((lkc ^ ((r >> 1) & 3)) << 4);
  }

  f32x4_v acc[FM][FN];
  #pragma unroll
  for (int f = 0; f < FM; ++f)
    #pragma unroll
    for (int n_ = 0; n_ < FN; ++n_) acc[f][n_] = (f32x4_v){0.f, 0.f, 0.f, 0.f};

  const int NT = K / BK;

  for (int tt = 0; tt < 3; ++tt) {
    char* sb = smem + tt * SLOT;
    #pragma unroll
    for (int j = 0; j < L; ++j)
      gload16((j < JA ? A : Bt) + soff[j] + tt * BK,
              (unsigned short*)(sb + (tid + j * 512) * 16));
  }
  VMCNT(8);
  __builtin_amdgcn_s_barrier();
  __builtin_amdgcn_sched_barrier(0);

  bf16x8 bfr[FN];
  for (int t = 0; t < NT; ++t) {
    const char* sb = smem + (t & 3) * SLOT;
    char* pb = smem + ((t + 3) & 3) * SLOT;
    const bool do_stage = (t + 3 < NT);
    #pragma unroll
    for (int p = 0; p < P; ++p) {
      bf16x8 af[4];
      #pragma unroll
      for (int m_ = 0; m_ < 4; ++m_)
        af[m_] = *(const bf16x8*)(sb + aoff[p * 4 + m_]);
      if (p == 0) {
        #pragma unroll
        for (int n_ = 0; n_ < FN; ++n_)
          bfr[n_] = *(const bf16x8*)(sb + boff[n_]);
      }
      if (do_stage) {
        #pragma unroll
        for (int jj = 0; jj < LPP; ++jj) {
          const int j = p * LPP + jj;
          gload16((j < JA ? A : Bt) + soff[j] + (t + 3) * BK,
                  (unsigned short*)(pb + (tid + j * 512) * 16));
        }
      }
      __builtin_amdgcn_s_barrier();
      __builtin_amdgcn_s_setprio(1);
      #pragma unroll
      for (int m_ = 0; m_ < 4; ++m_)
        #pragma unroll
        for (int n_ = 0; n_ < FN; ++n_)
          acc[p * 4 + m_][n_] = __builtin_amdgcn_mfma_f32_16x16x32_bf16(
              af[m_], bfr[n_], acc[p * 4 + m_][n_], 0, 0, 0);
      __builtin_amdgcn_s_setprio(0);
      if (p == P - 1) {
        if (t < NT - 3)       { VMCNT(8); }
        else if (t == NT - 3) { VMCNT(4); }
        else if (t == NT - 2) { VMCNT(0); }
      }
      __builtin_amdgcn_s_barrier();
      __builtin_amdgcn_sched_barrier(0);
    }
  }

  const int colq = l & 15;
  const int rowq = (l >> 4) * 4;
  #pragma unroll
  for (int f = 0; f < FM; ++f)
    #pragma unroll
    for (int n_ = 0; n_ < FN; ++n_) {
      const int col = n0 + wn * (BN / 4) + n_ * 16 + colq;
      #pragma unroll
      for (int r = 0; r < 4; ++r) {
        const int row = m0 + wm * (BM / 2) + f * 16 + rowq + r;
        Cbf[(size_t)row * N + col] = f2bf(gelu_fast(acc[f][n_][r]));
      }
    }
}

// ---------------------------------------------------------------------------
// g2: SAME 256x256 BK=32 template as g1 (L3-feed-optimal: 537 MB staged vs
// 786 MB at 128x256). Grid 128 = half machine; feed ~54us = MFMA floor ~55us.
// Epilogue: f32 out + bias.
// ---------------------------------------------------------------------------
__global__ __launch_bounds__(512)
void g2_kernel(const unsigned short* __restrict__ A,
               const unsigned short* __restrict__ Bt,
               float* __restrict__ Cf,
               const float* __restrict__ bias,
               const int* __restrict__ eidx_p)
{
  constexpr int BM = 256, BN = 256, BK = 32, CHM = 8, CHN = 2;
  constexpr int FM = 8, FN = 4;
  constexpr int P = 2;
  constexpr int SLOT = (BM + BN) * BK * 2;     // 32 KB
  constexpr int L = 4, LPP = 2;
  constexpr int ACH = BM * 4;                  // 1024
  constexpr int JA = 2;
  const int K = HDDIM, N = DMODEL;             // M=8192 N=1024 K=4096

  __shared__ __align__(16) char smem[4 * SLOT];  // 128 KB

  const int ncn = (N / BN) / CHN;              // 4/2 = 2
  const int xcd = blockIdx.x & 7;
  const int idx = blockIdx.x >> 3;             // 0..15
  const int bm  = (xcd / ncn) * CHM + idx / CHN;
  const int bn  = (xcd % ncn) * CHN + idx % CHN;
  const int m0 = bm * BM, n0 = bn * BN;

  const int tid = threadIdx.x;
  const int w = tid >> 6, l = tid & 63;
  const int wm = w >> 2, wn = w & 3;
  const int lrow = l & 15, lkc = l >> 4;

  uint32_t soff[L];
  #pragma unroll
  for (int j = 0; j < L; ++j) {
    const int q = tid + j * 512;
    if (j < JA) {
      const int r = q >> 2, cs = (q & 3) ^ ((r >> 1) & 3);
      soff[j] = (uint32_t)(m0 + r) * (uint32_t)K + cs * 8;
    } else {
      const int q2 = q - ACH;
      const int r = q2 >> 2, cs = (q2 & 3) ^ ((r >> 1) & 3);
      soff[j] = (uint32_t)(n0 + r) * (uint32_t)K + cs * 8;
    }
  }

  int aoff[FM], boff[FN];
  #pragma unroll
  for (int f = 0; f < FM; ++f) {
    const int r = wm * (BM / 2) + f * 16 + lrow;
    aoff[f] = r * 64 + ((lkc ^ ((r >> 1) & 3)) << 4);
  }
  #pragma unroll
  for (int n_ = 0; n_ < FN; ++n_) {
    const int r = wn * (BN / 4) + n_ * 16 + lrow;
    boff[n_] = BM * 64 + r * 64 + ((lkc ^ ((r >> 1) & 3)) << 4);
  }

  f32x4_v acc[FM][FN];
  #pragma unroll
  for (int f = 0; f < FM; ++f)
    #pragma unroll
    for (int n_ = 0; n_ < FN; ++n_) acc[f][n_] = (f32x4_v){0.f, 0.f, 0.f, 0.f};

  const int NT = K / BK;   // 128

  for (int tt = 0; tt < 3; ++tt) {
    char* sb = smem + tt * SLOT;
    #pragma unroll
    for (int j = 0; j < L; ++j)
      gload16((j < JA ? A : Bt) + soff[j] + tt * BK,
              (unsigned short*)(sb + (tid + j * 512) * 16));
  }
  VMCNT(8);
  __builtin_amdgcn_s_barrier();
  __builtin_amdgcn_sched_barrier(0);

  bf16x8 bfr[FN];
  for (int t = 0; t < NT; ++t) {
    const char* sb = smem + (t & 3) * SLOT;
    char* pb = smem + ((t + 3) & 3) * SLOT;
    const bool do_stage = (t + 3 < NT);
    #pragma unroll
    for (int p = 0; p < P; ++p) {
      bf16x8 af[4];
      #pragma unroll
      for (int m_ = 0; m_ < 4; ++m_)
        af[m_] = *(const bf16x8*)(sb + aoff[p * 4 + m_]);
      if (p == 0) {
        #pragma unroll
        for (int n_ = 0; n_ < FN; ++n_)
          bfr[n_] = *(const bf16x8*)(sb + boff[n_]);
      }
      if (do_stage) {
        #pragma unroll
        for (int jj = 0; jj < LPP; ++jj) {
          const int j = p * LPP + jj;
          gload16((j < JA ? A : Bt) + soff[j] + (t + 3) * BK,
                  (unsigned short*)(pb + (tid + j * 512) * 16));
        }
      }
      __builtin_amdgcn_s_barrier();
      __builtin_amdgcn_s_setprio(1);
      #pragma unroll
      for (int m_ = 0; m_ < 4; ++m_)
        #pragma unroll
        for (int n_ = 0; n_ < FN; ++n_)
          acc[p * 4 + m_][n_] = __builtin_amdgcn_mfma_f32_16x16x32_bf16(
              af[m_], bfr[n_], acc[p * 4 + m_][n_], 0, 0, 0);
      __builtin_amdgcn_s_setprio(0);
      if (p == P - 1) {
        if (t < NT - 3)       { VMCNT(8); }
        else if (t == NT - 3) { VMCNT(4); }
        else if (t == NT - 2) { VMCNT(0); }
      }
      __builtin_amdgcn_s_barrier();
      __builtin_amdgcn_sched_barrier(0);
    }
  }

  const int colq = l & 15;
  const int rowq = (l >> 4) * 4;
  const int e = *eidx_p;
  const float* brow = bias + (size_t)e * N;
  #pragma unroll
  for (int n_ = 0; n_ < FN; ++n_) {
    const int col = n0 + wn * (BN / 4) + n_ * 16 + colq;
    const float bv = brow[col];
    #pragma unroll
    for (int f = 0; f < FM; ++f)
      #pragma unroll
      for (int r = 0; r < 4; ++r) {
        const int row = m0 + wm * (BM / 2) + f * 16 + rowq + r;
        Cf[(size_t)row * N + col] = acc[f][n_][r] + bv;
      }
  }
}

// ---------------------------------------------------------------------------
extern "C" void kernel_launch(void* const* d_in, const int* in_sizes, int n_in,
                              void* d_out, int out_size, void* d_ws, size_t ws_size,
                              hipStream_t stream)
{
  const float* inputs     = (const float*)d_in[0];
  const float* basis_up   = (const float*)d_in[1];
  const float* basis_down = (const float*)d_in[2];
  const float* cup        = (const float*)d_in[3];
  const float* cdn        = (const float*)d_in[4];
  const float* bias       = (const float*)d_in[5];
  const int*   eidx       = (const int*)d_in[6];
  float*       out        = (float*)d_out;

  char* ws = (char*)d_ws;
  unsigned short* A_bf   = (unsigned short*)(ws);                  // 16 MB
  unsigned short* hidden = (unsigned short*)(ws + (16u << 20));    // 64 MB
  unsigned short* WupT   = (unsigned short*)(ws + (80u << 20));    //  8 MB
  unsigned short* WdnT   = (unsigned short*)(ws + (88u << 20));    //  8 MB

  // P1: rec_up + cvt (HBM-bound)
  p1_kernel<<<1536, 256, 0, stream>>>(
      inputs, basis_up, cup, eidx, A_bf, WupT);

  // P2: g1 (even blocks) overlapped with rec_dn (odd blocks)
  p2_kernel<<<1024, 512, 0, stream>>>(
      A_bf, WupT, hidden, basis_down, cdn, eidx, WdnT);

  // P3: out = hidden @ WdnT^T + bias   (256x256 tile, minimal L3 feed)
  g2_kernel<<<128, 512, 0, stream>>>(
      hidden, WdnT, out, bias, eidx);
}

// Round 16
// 318.414 us; speedup vs baseline: 1.1334x; 1.1334x over previous
//
#include <hip/hip_runtime.h>
#include <cstdint>

#define NTOK 8192
#define DMODEL 1024
#define HDDIM 4096
#define NVEC 32

typedef float f32x4_v __attribute__((ext_vector_type(4)));
typedef __bf16 bf16x8 __attribute__((ext_vector_type(8)));
typedef unsigned short u16x4 __attribute__((ext_vector_type(4)));
typedef unsigned short u16x8 __attribute__((ext_vector_type(8)));

__device__ __forceinline__ unsigned short f2bf(float f) {
  union { float f; uint32_t u; } x; x.f = f;
  uint32_t r = (x.u + 0x7FFFu + ((x.u >> 16) & 1u)) >> 16;
  return (unsigned short)r;
}

__device__ __forceinline__ float gelu_fast(float x) {
  float t = x * x;
  float z = x * (2.3022082f + 0.1029440f * t);
  float e = exp2f(-z);
  return x / (1.0f + e);
}

#define VMCNT(n) asm volatile("s_waitcnt vmcnt(" #n ")" ::: "memory")

__device__ __forceinline__ void gload16(const unsigned short* g, unsigned short* lds)
{
  __builtin_amdgcn_global_load_lds((__attribute__((address_space(1))) void*)g,
                                   (__attribute__((address_space(3))) void*)lds,
                                   16, 0, 0);
}

// ---------------------------------------------------------------------------
// Reconstruct + transpose body: tile 16x256, staggered v (R12 config).
// outT[y][x] (bf16, ld=X) = sum_v c[v]*basis[v][x][y]
// ---------------------------------------------------------------------------
__device__ __forceinline__
void reconstruct_body(const float* __restrict__ basis,
                      const float* __restrict__ coeffs,
                      int e, unsigned short* __restrict__ outT,
                      int X, int Y, int tile, int stag, char* smem, int t)
{
  float (*lds)[260] = (float (*)[260])smem;
  const int xtiles = X >> 4;
  const int bx = tile % xtiles;
  const int by = tile / xtiles;
  const int x0 = bx << 4, y0 = by << 8;
  const int w  = t >> 6, l = t & 63;

  f32x4_v acc[4];
  #pragma unroll
  for (int i = 0; i < 4; ++i) acc[i] = (f32x4_v){0.f, 0.f, 0.f, 0.f};

  const size_t mat = (size_t)X * (size_t)Y;
  uint32_t roff[4];
  #pragma unroll
  for (int i = 0; i < 4; ++i)
    roff[i] = (uint32_t)(x0 + w * 4 + i) * (uint32_t)Y + (uint32_t)(y0 + l * 4);

  #pragma unroll 4
  for (int vv = 0; vv < NVEC; ++vv) {
    const int v = (vv + stag) & (NVEC - 1);
    const float cv = coeffs[e * NVEC + v];
    const float* pv = basis + (size_t)v * mat;
    #pragma unroll
    for (int i = 0; i < 4; ++i) {
      f32x4_v d = __builtin_nontemporal_load((const f32x4_v*)(pv + roff[i]));
      acc[i] += cv * d;
    }
  }

  #pragma unroll
  for (int i = 0; i < 4; ++i)
    *(f32x4_v*)&lds[w * 4 + i][l * 4] = acc[i];
  __syncthreads();

  const int y = y0 + t;
  u16x8 o0, o1;
  #pragma unroll
  for (int x = 0; x < 8; ++x)  o0[x] = f2bf(lds[x][t]);
  #pragma unroll
  for (int x = 0; x < 8; ++x)  o1[x] = f2bf(lds[8 + x][t]);
  unsigned short* dst = outT + (size_t)y * X + x0;
  *(u16x8*)dst = o0;
  *(u16x8*)(dst + 8) = o1;
}

// ---------------------------------------------------------------------------
// Phase 1: rec_up (0..1023) | cvt (1024..1535).  256 threads.
// ---------------------------------------------------------------------------
__global__ __launch_bounds__(256)
void p1_kernel(const float* __restrict__ inputs,
               const float* __restrict__ basis_up,
               const float* __restrict__ cup,
               const int* __restrict__ eidx_p,
               unsigned short* __restrict__ A_bf,
               unsigned short* __restrict__ WupT)
{
  __shared__ __align__(16) char smem[16 * 260 * 4];
  const int bid = blockIdx.x;
  if (bid < 1024) {
    reconstruct_body(basis_up, cup, *eidx_p, WupT, DMODEL, HDDIM, bid, bid,
                     smem, threadIdx.x);
  } else {
    const int n4 = NTOK * DMODEL / 4;
    const int stride = 512 * 256;
    for (int i = (bid - 1024) * 256 + threadIdx.x; i < n4; i += stride) {
      f32x4_v v = ((const f32x4_v*)inputs)[i];
      u16x4 u;
      #pragma unroll
      for (int j = 0; j < 4; ++j) u[j] = f2bf(v[j]);
      ((u16x4*)A_bf)[i] = u;
    }
  }
}

// ---------------------------------------------------------------------------
// Phase 2: g1 (even bids) OVERLAPPED with rec_dn (odd bids). Round-robin
// dispatch puts g1 on XCDs {0,2,4,6}, rec on {1,3,5,7}. 128 KB LDS ->
// 1 block/CU -> device-level CU partitioning.
// ---------------------------------------------------------------------------
__global__ __launch_bounds__(512)
void p2_kernel(const unsigned short* __restrict__ A,
               const unsigned short* __restrict__ Bt,
               unsigned short* __restrict__ Cbf,
               const float* __restrict__ basis_down,
               const float* __restrict__ cdn,
               const int* __restrict__ eidx_p,
               unsigned short* __restrict__ WdnT)
{
  constexpr int BM = 256, BN = 256, BK = 32, CHM = 8, CHN = 8;
  constexpr int FM = BM / 32, FN = BN / 64;
  constexpr int P = (FM * FN) / 16;
  constexpr int SLOT = (BM + BN) * BK * 2;     // 32 KB
  constexpr int L = SLOT / 16 / 512;           // 4
  constexpr int LPP = L / P;
  constexpr int ACH = BM * 4;
  constexpr int JA = ACH / 512;                // 2

  __shared__ __align__(16) char smem[4 * SLOT];  // 128 KB

  const int bid = blockIdx.x;

  if (bid & 1) {
    const int half = threadIdx.x >> 8;
    const int tile = (bid >> 1) * 2 + half;
    reconstruct_body(basis_down, cdn, *eidx_p, WdnT, HDDIM, DMODEL,
                     tile, bid + half, smem + half * 16640, threadIdx.x & 255);
    return;
  }

  const int gtile = bid >> 1;
  const int K = DMODEL, N = HDDIM;
  const int ncn = (N / BN) / CHN;
  const int xcd = gtile & 7;
  const int idx = gtile >> 3;
  const int bm  = (xcd / ncn) * CHM + idx / CHN;
  const int bn  = (xcd % ncn) * CHN + idx % CHN;
  const int m0 = bm * BM, n0 = bn * BN;

  const int tid = threadIdx.x;
  const int w = tid >> 6, l = tid & 63;
  const int wm = w >> 2, wn = w & 3;
  const int lrow = l & 15, lkc = l >> 4;

  uint32_t soff[L];
  #pragma unroll
  for (int j = 0; j < L; ++j) {
    const int q = tid + j * 512;
    if (j < JA) {
      const int r = q >> 2, cs = (q & 3) ^ ((r >> 1) & 3);
      soff[j] = (uint32_t)(m0 + r) * (uint32_t)K + cs * 8;
    } else {
      const int q2 = q - ACH;
      const int r = q2 >> 2, cs = (q2 & 3) ^ ((r >> 1) & 3);
      soff[j] = (uint32_t)(n0 + r) * (uint32_t)K + cs * 8;
    }
  }

  int aoff[FM], boff[FN];
  #pragma unroll
  for (int f = 0; f < FM; ++f) {
    const int r = wm * (BM / 2) + f * 16 + lrow;
    aoff[f] = r * 64 + ((lkc ^ ((r >> 1) & 3)) << 4);
  }
  #pragma unroll
  for (int n_ = 0; n_ < FN; ++n_) {
    const int r = wn * (BN / 4) + n_ * 16 + lrow;
    boff[n_] = BM * 64 + r * 64 + ((lkc ^ ((r >> 1) & 3)) << 4);
  }

  f32x4_v acc[FM][FN];
  #pragma unroll
  for (int f = 0; f < FM; ++f)
    #pragma unroll
    for (int n_ = 0; n_ < FN; ++n_) acc[f][n_] = (f32x4_v){0.f, 0.f, 0.f, 0.f};

  const int NT = K / BK;

  for (int tt = 0; tt < 3; ++tt) {
    char* sb = smem + tt * SLOT;
    #pragma unroll
    for (int j = 0; j < L; ++j)
      gload16((j < JA ? A : Bt) + soff[j] + tt * BK,
              (unsigned short*)(sb + (tid + j * 512) * 16));
  }
  VMCNT(8);
  __builtin_amdgcn_s_barrier();
  __builtin_amdgcn_sched_barrier(0);

  bf16x8 bfr[FN];
  for (int t = 0; t < NT; ++t) {
    const char* sb = smem + (t & 3) * SLOT;
    char* pb = smem + ((t + 3) & 3) * SLOT;
    const bool do_stage = (t + 3 < NT);
    #pragma unroll
    for (int p = 0; p < P; ++p) {
      bf16x8 af[4];
      #pragma unroll
      for (int m_ = 0; m_ < 4; ++m_)
        af[m_] = *(const bf16x8*)(sb + aoff[p * 4 + m_]);
      if (p == 0) {
        #pragma unroll
        for (int n_ = 0; n_ < FN; ++n_)
          bfr[n_] = *(const bf16x8*)(sb + boff[n_]);
      }
      if (do_stage) {
        #pragma unroll
        for (int jj = 0; jj < LPP; ++jj) {
          const int j = p * LPP + jj;
          gload16((j < JA ? A : Bt) + soff[j] + (t + 3) * BK,
                  (unsigned short*)(pb + (tid + j * 512) * 16));
        }
      }
      __builtin_amdgcn_s_barrier();
      __builtin_amdgcn_s_setprio(1);
      #pragma unroll
      for (int m_ = 0; m_ < 4; ++m_)
        #pragma unroll
        for (int n_ = 0; n_ < FN; ++n_)
          acc[p * 4 + m_][n_] = __builtin_amdgcn_mfma_f32_16x16x32_bf16(
              af[m_], bfr[n_], acc[p * 4 + m_][n_], 0, 0, 0);
      __builtin_amdgcn_s_setprio(0);
      if (p == P - 1) {
        if (t < NT - 3)       { VMCNT(8); }
        else if (t == NT - 3) { VMCNT(4); }
        else if (t == NT - 2) { VMCNT(0); }
      }
      __builtin_amdgcn_s_barrier();
      __builtin_amdgcn_sched_barrier(0);
    }
  }

  const int colq = l & 15;
  const int rowq = (l >> 4) * 4;
  #pragma unroll
  for (int f = 0; f < FM; ++f)
    #pragma unroll
    for (int n_ = 0; n_ < FN; ++n_) {
      const int col = n0 + wn * (BN / 4) + n_ * 16 + colq;
      #pragma unroll
      for (int r = 0; r < 4; ++r) {
        const int row = m0 + wm * (BM / 2) + f * 16 + rowq + r;
        Cbf[(size_t)row * N + col] = f2bf(gelu_fast(acc[f][n_][r]));
      }
    }
}

// ---------------------------------------------------------------------------
// g2: BM=128 BN=256 BK=64, 3-slot ring, lead-2, P=2, R12 chunk map (best
// measured: ~87us; 5 alternative theories probed null/regress).
// ---------------------------------------------------------------------------
template<int CHM, int CHN>
__global__ __launch_bounds__(512)
void gemm_k64(const unsigned short* __restrict__ A,
              const unsigned short* __restrict__ Bt,
              float* __restrict__ Cf,
              const float* __restrict__ bias,
              const int* __restrict__ eidx_p,
              int M, int N, int K)
{
  constexpr int BM = 128, BN = 256, BK = 64;
  constexpr int SLOT = (BM + BN) * BK * 2;
  constexpr int L = 6, JA = 2;
  __shared__ __align__(16) char smem[3 * SLOT];

  const int nb  = N / BN;
  const int ncn = nb / CHN;
  const int xcd = blockIdx.x & 7;
  const int idx = blockIdx.x >> 3;
  const int bm  = (xcd / ncn) * CHM + idx / CHN;
  const int bn  = (xcd % ncn) * CHN + idx % CHN;
  const int m0 = bm * BM, n0 = bn * BN;

  const int tid = threadIdx.x;
  const int w = tid >> 6, l = tid & 63;
  const int wm = w >> 2, wn = w & 3;
  const int lrow = l & 15, lkc = l >> 4;

  uint32_t soff[L];
  #pragma unroll
  for (int j = 0; j < L; ++j) {
    const int q = tid + j * 512;
    if (j < JA) {
      const int r = q >> 3, cs = (q & 7) ^ (r & 7);
      soff[j] = (uint32_t)(m0 + r) * (uint32_t)K + cs * 8;
    } else {
      const int q2 = q - 1024;
      const int r = q2 >> 3, cs = (q2 & 7) ^ (r & 7);
      soff[j] = (uint32_t)(n0 + r) * (uint32_t)K + cs * 8;
    }
  }

  int abase[4], aswz[4], bbase[4], bswz[4];
  #pragma unroll
  for (int f = 0; f < 4; ++f) {
    const int r = wm * 64 + f * 16 + lrow;
    abase[f] = r * 128; aswz[f] = r & 7;
  }
  #pragma unroll
  for (int n_ = 0; n_ < 4; ++n_) {
    const int r = wn * 64 + n_ * 16 + lrow;
    bbase[n_] = 16384 + r * 128; bswz[n_] = r & 7;
  }

  f32x4_v acc[4][4];
  #pragma unroll
  for (int f = 0; f < 4; ++f)
    #pragma unroll
    for (int n_ = 0; n_ < 4; ++n_) acc[f][n_] = (f32x4_v){0.f, 0.f, 0.f, 0.f};

  const int NT = K / BK;

  for (int tt = 0; tt < 2; ++tt) {
    char* sb = smem + tt * SLOT;
    #pragma unroll
    for (int j = 0; j < L; ++j)
      gload16((j < JA ? A : Bt) + soff[j] + tt * BK,
              (unsigned short*)(sb + (tid + j * 512) * 16));
  }
  VMCNT(6);
  __builtin_amdgcn_s_barrier();
  __builtin_amdgcn_sched_barrier(0);

  int cur = 0, pf = 2;
  for (int t = 0; t < NT; ++t) {
    const char* sb = smem + cur * SLOT;
    char* pb = smem + pf * SLOT;
    const bool do_stage = (t + 2 < NT);
    #pragma unroll
    for (int p = 0; p < 2; ++p) {
      bf16x8 af[4], bfr[4];
      #pragma unroll
      for (int m_ = 0; m_ < 4; ++m_)
        af[m_] = *(const bf16x8*)(sb + abase[m_] + ((((p << 2) + lkc) ^ aswz[m_]) << 4));
      #pragma unroll
      for (int n_ = 0; n_ < 4; ++n_)
        bfr[n_] = *(const bf16x8*)(sb + bbase[n_] + ((((p << 2) + lkc) ^ bswz[n_]) << 4));
      if (do_stage) {
        #pragma unroll
        for (int jj = 0; jj < 3; ++jj) {
          const int j = p * 3 + jj;
          gload16((j < JA ? A : Bt) + soff[j] + (t + 2) * BK,
                  (unsigned short*)(pb + (tid + j * 512) * 16));
        }
      }
      __builtin_amdgcn_s_barrier();
      __builtin_amdgcn_s_setprio(1);
      #pragma unroll
      for (int m_ = 0; m_ < 4; ++m_)
        #pragma unroll
        for (int n_ = 0; n_ < 4; ++n_)
          acc[m_][n_] = __builtin_amdgcn_mfma_f32_16x16x32_bf16(
              af[m_], bfr[n_], acc[m_][n_], 0, 0, 0);
      __builtin_amdgcn_s_setprio(0);
      if (p == 1) {
        if (t < NT - 2)       { VMCNT(6); }
        else if (t == NT - 2) { VMCNT(0); }
      }
      __builtin_amdgcn_s_barrier();
      __builtin_amdgcn_sched_barrier(0);
    }
    cur = (cur == 2) ? 0 : cur + 1;
    pf  = (pf == 2) ? 0 : pf + 1;
  }

  const int colq = l & 15;
  const int rowq = (l >> 4) * 4;
  const int e = *eidx_p;
  const float* brow = bias + (size_t)e * N;
  #pragma unroll
  for (int n_ = 0; n_ < 4; ++n_) {
    const int col = n0 + wn * 64 + n_ * 16 + colq;
    const float bv = brow[col];
    #pragma unroll
    for (int f = 0; f < 4; ++f)
      #pragma unroll
      for (int r = 0; r < 4; ++r) {
        const int row = m0 + wm * 64 + f * 16 + rowq + r;
        Cf[(size_t)row * N + col] = acc[f][n_][r] + bv;
      }
  }
}

// ---------------------------------------------------------------------------
extern "C" void kernel_launch(void* const* d_in, const int* in_sizes, int n_in,
                              void* d_out, int out_size, void* d_ws, size_t ws_size,
                              hipStream_t stream)
{
  const float* inputs     = (const float*)d_in[0];
  const float* basis_up   = (const float*)d_in[1];
  const float* basis_down = (const float*)d_in[2];
  const float* cup        = (const float*)d_in[3];
  const float* cdn        = (const float*)d_in[4];
  const float* bias       = (const float*)d_in[5];
  const int*   eidx       = (const int*)d_in[6];
  float*       out        = (float*)d_out;

  char* ws = (char*)d_ws;
  unsigned short* A_bf   = (unsigned short*)(ws);                  // 16 MB
  unsigned short* hidden = (unsigned short*)(ws + (16u << 20));    // 64 MB
  unsigned short* WupT   = (unsigned short*)(ws + (80u << 20));    //  8 MB
  unsigned short* WdnT   = (unsigned short*)(ws + (88u << 20));    //  8 MB

  // P1: rec_up + cvt (HBM-bound)
  p1_kernel<<<1536, 256, 0, stream>>>(
      inputs, basis_up, cup, eidx, A_bf, WupT);

  // P2: g1 (even blocks) overlapped with rec_dn (odd blocks)
  p2_kernel<<<1024, 512, 0, stream>>>(
      A_bf, WupT, hidden, basis_down, cdn, eidx, WdnT);

  // P3: out = hidden @ WdnT^T + bias
  gemm_k64<8, 4><<<256, 512, 0, stream>>>(
      hidden, WdnT, out, bias, eidx, NTOK, DMODEL, HDDIM);
}